// Round 7
// baseline (26970.929 us; speedup 1.0000x reference)
//
#include <hip/hip_runtime.h>
#include <hip/hip_bf16.h>

#define S_LEN 40
#define NB    256
#define EDIM  1024
#define HDIM  1024
#define NBLK  512

typedef _Float16 f16;
typedef __attribute__((ext_vector_type(8))) _Float16 f16x8;
typedef __attribute__((ext_vector_type(4))) _Float16 f16x4;
typedef __attribute__((ext_vector_type(4))) float f32x4;

__device__ __forceinline__ float sigm(float x) {
    x = fminf(fmaxf(x, -30.f), 30.f);
    return 1.f / (1.f + __expf(-x));
}
__device__ __forceinline__ float tanh_fast(float x) {
    x = fminf(fmaxf(x, -15.f), 15.f);
    float e = __expf(2.f * x);
    return (e - 1.f) / (e + 1.f);
}

// Layout-robust probe: A[i][k]=i, B[k][j]=1/32 -> D[i][j]=i regardless of
// fragment k-ordering (C/D layout is dtype-independent on gfx950).
__device__ __forceinline__ void probe_mn(int lane, int* mrow, int* ncol) {
    f16x8 pa, pb;
#pragma unroll
    for (int e = 0; e < 8; e++) {
        pa[e] = (f16)(float)(lane & 15);
        pb[e] = (f16)0.03125f;
    }
    f32x4 pacc = {0, 0, 0, 0};
    pacc = __builtin_amdgcn_mfma_f32_16x16x32_f16(pa, pb, pacc, 0, 0, 0);
#pragma unroll
    for (int r = 0; r < 4; r++) {
        int m = (int)(pacc[r] + 0.5f);
        int cg = ((lane >> 4) << 2) + r;
        mrow[r] = m;
        ncol[r] = (m == cg) ? (lane & 15) : cg;
    }
}

// ---------------- grid barrier (generation-based, agent scope) -------------
__device__ __forceinline__ void gbar(unsigned* cnt, unsigned* gen) {
    __syncthreads();
    if (threadIdx.x == 0) {
        __threadfence();
        unsigned g = __hip_atomic_load(gen, __ATOMIC_RELAXED, __HIP_MEMORY_SCOPE_AGENT);
        unsigned a = __hip_atomic_fetch_add(cnt, 1u, __ATOMIC_ACQ_REL, __HIP_MEMORY_SCOPE_AGENT);
        if (a == NBLK - 1) {
            __hip_atomic_store(cnt, 0u, __ATOMIC_RELAXED, __HIP_MEMORY_SCOPE_AGENT);
            __hip_atomic_fetch_add(gen, 1u, __ATOMIC_RELEASE, __HIP_MEMORY_SCOPE_AGENT);
        } else {
            while (__hip_atomic_load(gen, __ATOMIC_ACQUIRE, __HIP_MEMORY_SCOPE_AGENT) == g)
                __builtin_amdgcn_s_sleep(8);
        }
        __threadfence();
    }
    __syncthreads();
}

__global__ void k_init_sync(unsigned* s) { s[0] = 0; s[1] = 0; }

// ---------------- f32 -> f16 convert, 4 elems/thread -----------------------
__global__ __launch_bounds__(256) void k_cvt4(const float* __restrict__ src,
                                              f16* __restrict__ dst, int n4) {
    int i = blockIdx.x * 256 + threadIdx.x;
    if (i < n4) {
        float4 v = ((const float4*)src)[i];
        f16x4 o = {(f16)v.x, (f16)v.y, (f16)v.z, (f16)v.w};
        ((f16x4*)dst)[i] = o;
    }
}

__global__ __launch_bounds__(256) void k_copyf4(const float* __restrict__ src,
                                                float* __restrict__ dst, int n4) {
    int i = blockIdx.x * 256 + threadIdx.x;
    if (i < n4) ((float4*)dst)[i] = ((const float4*)src)[i];
}

__global__ __launch_bounds__(256) void k_embed_cvt(const int* __restrict__ tok,
                                                   const float* __restrict__ emb,
                                                   f16* __restrict__ xe) {
    int b = blockIdx.x;
    int t = threadIdx.x;
    int token = tok[b];
    float4 v = ((const float4*)(emb + (size_t)token * EDIM))[t];
    f16x4 o = {(f16)v.x, (f16)v.y, (f16)v.z, (f16)v.w};
    ((f16x4*)(xe + (size_t)b * EDIM))[t] = o;
}

// ---------------- GRU cell 32x32 tile (encoder), 12 waves ------------------
// tb in [0,256): cb=(tb&31)*32, rb=(tb>>5)*32. wave = pair(0..5) x khalf(0..1)
__device__ void gru32(
    int tb, int tid, const int* mr, const int* nc, float* red,
    const f16* x16, const f16* h16_in, const float* hf_in,
    const f16* wih, const f16* whh,
    const float* bih, const float* bhh,
    f16* h16_out, float* hf_out, f16* o2_16, float* o2_f) {
    const int w = tid >> 6;
    const int lane = tid & 63;
    const int pair = w >> 1;
    const int kh = w & 1;
    const int cb = (tb & 31) * 32;
    const int rb = (tb >> 5) * 32;
    const int gate = (pair >= 3) ? (pair - 3) : pair;
    const int r0 = lane & 15;
    const int kk0 = (lane >> 4) * 8;

    const f16* A = (pair < 3) ? x16 : h16_in;
    const f16* B = ((pair < 3) ? wih : whh) + ((size_t)gate * HDIM + cb) * 1024;
    const size_t arow = (size_t)(rb + r0) * 1024 + kk0 + kh * 512;
    const size_t brow = (size_t)r0 * 1024 + kk0 + kh * 512;

    f32x4 acc00 = {0,0,0,0}, acc01 = {0,0,0,0}, acc10 = {0,0,0,0}, acc11 = {0,0,0,0};
#pragma unroll 4
    for (int k = 0; k < 512; k += 32) {
        f16x8 a0 = *(const f16x8*)(A + arow + k);
        f16x8 a1 = *(const f16x8*)(A + arow + 16 * 1024 + k);
        f16x8 b0 = *(const f16x8*)(B + brow + k);
        f16x8 b1 = *(const f16x8*)(B + brow + 16 * 1024 + k);
        acc00 = __builtin_amdgcn_mfma_f32_16x16x32_f16(a0, b0, acc00, 0, 0, 0);
        acc01 = __builtin_amdgcn_mfma_f32_16x16x32_f16(a0, b1, acc01, 0, 0, 0);
        acc10 = __builtin_amdgcn_mfma_f32_16x16x32_f16(a1, b0, acc10, 0, 0, 0);
        acc11 = __builtin_amdgcn_mfma_f32_16x16x32_f16(a1, b1, acc11, 0, 0, 0);
    }

    float* rw = red + w * 1024;
#pragma unroll
    for (int r = 0; r < 4; r++) {
        rw[mr[r] * 32 + nc[r]]              = acc00[r];
        rw[mr[r] * 32 + nc[r] + 16]         = acc01[r];
        rw[(mr[r] + 16) * 32 + nc[r]]       = acc10[r];
        rw[(mr[r] + 16) * 32 + nc[r] + 16]  = acc11[r];
    }
    __syncthreads();

    for (int i = tid; i < 1024; i += 768) {
        int rr = i >> 5, cc = i & 31;
        int col = cb + cc;
        int row = rb + rr;
        float gir = red[i]         + red[1024 + i];
        float giz = red[2048 + i]  + red[3072 + i];
        float gin = red[4096 + i]  + red[5120 + i];
        float ghr = red[6144 + i]  + red[7168 + i];
        float ghz = red[8192 + i]  + red[9216 + i];
        float ghn = red[10240 + i] + red[11264 + i];
        float r = sigm(gir + bih[col] + ghr + bhh[col]);
        float z = sigm(giz + bih[HDIM + col] + ghz + bhh[HDIM + col]);
        float n = tanh_fast(gin + bih[2 * HDIM + col] +
                            r * (ghn + bhh[2 * HDIM + col]));
        float hp = hf_in[(size_t)row * HDIM + col];
        float hn2 = (1.f - z) * n + z * hp;
        size_t idx = (size_t)row * HDIM + col;
        h16_out[idx] = (f16)hn2;
        hf_out[idx] = hn2;
        if (o2_16) o2_16[idx] = (f16)hn2;
        if (o2_f) o2_f[idx] = hn2;
    }
}

// ---------------- GRU cell 32x16 tile (decoder), 512 blocks, 12 waves ------
__device__ void gru16(
    int bid, int tid, const int* mr, const int* nc, float* red,
    const f16* x16, const f16* h16_in, const float* hf_in,
    const f16* wih, const f16* whh,
    const float* bih, const float* bhh,
    f16* h16_out, float* hf_out, float* o2_f) {
    const int w = tid >> 6;
    const int lane = tid & 63;
    const int pair = w >> 1;
    const int kh = w & 1;
    const int cb = (bid & 63) * 16;
    const int rb = (bid >> 6) * 32;
    const int gate = (pair >= 3) ? (pair - 3) : pair;
    const int r0 = lane & 15;
    const int kk0 = (lane >> 4) * 8;

    const f16* A = (pair < 3) ? x16 : h16_in;
    const f16* B = ((pair < 3) ? wih : whh) + ((size_t)gate * HDIM + cb) * 1024;
    const size_t arow = (size_t)(rb + r0) * 1024 + kk0 + kh * 512;
    const size_t brow = (size_t)r0 * 1024 + kk0 + kh * 512;

    f32x4 acc0 = {0,0,0,0}, acc1 = {0,0,0,0};
#pragma unroll 4
    for (int k = 0; k < 512; k += 32) {
        f16x8 a0 = *(const f16x8*)(A + arow + k);
        f16x8 a1 = *(const f16x8*)(A + arow + 16 * 1024 + k);
        f16x8 b0 = *(const f16x8*)(B + brow + k);
        acc0 = __builtin_amdgcn_mfma_f32_16x16x32_f16(a0, b0, acc0, 0, 0, 0);
        acc1 = __builtin_amdgcn_mfma_f32_16x16x32_f16(a1, b0, acc1, 0, 0, 0);
    }

    float* rw = red + w * 512;
#pragma unroll
    for (int r = 0; r < 4; r++) {
        rw[mr[r] * 16 + nc[r]]            = acc0[r];
        rw[(mr[r] + 16) * 16 + nc[r]]     = acc1[r];
    }
    __syncthreads();

    if (tid < 512) {
        int rr = tid >> 4, cc = tid & 15;
        int col = cb + cc;
        int row = rb + rr;
        float gir = red[tid]        + red[512 + tid];
        float giz = red[1024 + tid] + red[1536 + tid];
        float gin = red[2048 + tid] + red[2560 + tid];
        float ghr = red[3072 + tid] + red[3584 + tid];
        float ghz = red[4096 + tid] + red[4608 + tid];
        float ghn = red[5120 + tid] + red[5632 + tid];
        float r = sigm(gir + bih[col] + ghr + bhh[col]);
        float z = sigm(giz + bih[HDIM + col] + ghz + bhh[HDIM + col]);
        float n = tanh_fast(gin + bih[2 * HDIM + col] +
                            r * (ghn + bhh[2 * HDIM + col]));
        float hp = hf_in[(size_t)row * HDIM + col];
        float hn2 = (1.f - z) * n + z * hp;
        size_t idx = (size_t)row * HDIM + col;
        h16_out[idx] = (f16)hn2;
        hf_out[idx] = hn2;
        if (o2_f) o2_f[idx] = hn2;
    }
    __syncthreads();
}

// ---------------- attention phase: 512 blocks = 256 rows x 2 col halves ----
__device__ void attn_phase(
    int bid, int tid,
    const f16* xe_t, const f16* h0, const f16* h1,
    const f16* attn_w, const float* attn_b, const f16* enc16,
    f16* xcat) {
    __shared__ float logit[S_LEN];
    __shared__ float awls[S_LEN];
    const int n = bid & 255;
    const int g = bid >> 8;
    const int w = tid >> 6, lane = tid & 63;
    const size_t nrow = (size_t)n * 1024;
    const f16* xr = xe_t + nrow;
    const f16* h0r = h0 + nrow;
    const f16* h1r = h1 + nrow;

    // emb half: this block writes xcat[n][g*512 .. g*512+512)
    if (tid < 64) {
        ((f16x8*)(xcat + (size_t)n * 2048 + g * 512))[tid] =
            ((const f16x8*)(xr + g * 512))[tid];
    }

    // logits (computed redundantly by both g blocks), waves 0..9 x 4 rows
    if (w < 10) {
#pragma unroll
        for (int si = 0; si < 4; si++) {
            int s = w * 4 + si;
            const f16* wrow = attn_w + (size_t)s * 3072;
            float acc = 0.f;
#pragma unroll
            for (int j = lane; j < 384; j += 64) {
                const f16* sp = (j < 128) ? (xr + (j << 3))
                              : (j < 256) ? (h0r + ((j - 128) << 3))
                                          : (h1r + ((j - 256) << 3));
                f16x8 a = *(const f16x8*)sp;
                f16x8 b = *(const f16x8*)(wrow + (j << 3));
#pragma unroll
                for (int e = 0; e < 8; e++)
                    acc = fmaf((float)a[e], (float)b[e], acc);
            }
            for (int o = 32; o; o >>= 1) acc += __shfl_down(acc, o);
            if (lane == 0) logit[s] = acc + attn_b[s];
        }
    }
    __syncthreads();

    if (w == 0) {
        float v = (lane < S_LEN) ? logit[lane] : -1e30f;
        float m = v;
        for (int o = 32; o; o >>= 1) m = fmaxf(m, __shfl_xor(m, o));
        float e = (lane < S_LEN) ? __expf(v - m) : 0.f;
        float sum = e;
        for (int o = 32; o; o >>= 1) sum += __shfl_xor(sum, o);
        if (lane < S_LEN) awls[lane] = e / sum;
    }
    __syncthreads();

    // context: this block computes applied[g*512 + tid] over all 40 s
    if (tid < 512) {
        int col = g * 512 + tid;
        float acc = 0.f;
#pragma unroll
        for (int s = 0; s < S_LEN; s++)
            acc = fmaf(awls[s], (float)enc16[(((size_t)s * NB + n) << 10) + col], acc);
        xcat[(size_t)n * 2048 + 1024 + col] = (f16)acc;
    }
    __syncthreads();
}

// ---------------- comb phase: 512 blocks 32x16 tiles, 12-way K split -------
__device__ void comb_phase(
    int bid, int tid, const int* mr, const int* nc, float* red,
    const f16* A, const f16* B, const float* bias, f16* C) {
    const int w = tid >> 6, lane = tid & 63;
    const int cb = (bid & 63) * 16;
    const int rb = (bid >> 6) * 32;
    const int K = 2048;
    const int c0 = (w * 64) / 12, c1 = ((w + 1) * 64) / 12;
    const int r0 = lane & 15, kk0 = (lane >> 4) * 8;

    f32x4 acc0 = {0,0,0,0}, acc1 = {0,0,0,0};
    const size_t aoff = (size_t)(rb + r0) * K + kk0;
    const size_t boff = (size_t)(cb + r0) * K + kk0;

    for (int c = c0; c < c1; c++) {
        int k = c * 32;
        f16x8 a0 = *(const f16x8*)(A + aoff + k);
        f16x8 a1 = *(const f16x8*)(A + aoff + 16 * K + k);
        f16x8 b0 = *(const f16x8*)(B + boff + k);
        acc0 = __builtin_amdgcn_mfma_f32_16x16x32_f16(a0, b0, acc0, 0, 0, 0);
        acc1 = __builtin_amdgcn_mfma_f32_16x16x32_f16(a1, b0, acc1, 0, 0, 0);
    }

    float* rw = red + w * 512;
#pragma unroll
    for (int r = 0; r < 4; r++) {
        rw[mr[r] * 16 + nc[r]]        = acc0[r];
        rw[(mr[r] + 16) * 16 + nc[r]] = acc1[r];
    }
    __syncthreads();

    if (tid < 512) {
        float s = 0.f;
#pragma unroll
        for (int p = 0; p < 12; p++) s += red[p * 512 + tid];
        int rr = tid >> 4, cc = tid & 15;
        s += bias[cb + cc];
        s = fmaxf(s, 0.f);
        C[(size_t)(rb + rr) * 1024 + cb + cc] = (f16)s;
    }
    __syncthreads();
}

// ---------------- the mega kernel ------------------------------------------
__global__ __launch_bounds__(768, 6) void k_mega(
    const f16* __restrict__ xe,
    f16* h16, float* hf,
    const f16* __restrict__ w_eih, const f16* __restrict__ w_ehh,
    const float* __restrict__ enc_bih, const float* __restrict__ enc_bhh,
    const f16* __restrict__ w_dih, const f16* __restrict__ w_dhh,
    const float* __restrict__ dec_bih, const float* __restrict__ dec_bhh,
    const f16* __restrict__ w_attn, const float* __restrict__ attn_b,
    const f16* __restrict__ w_comb, const float* __restrict__ comb_b,
    f16* enc16, f16* xcat, f16* xcur,
    float* out, unsigned* sync) {
    __shared__ float red[12 * 1024];
    const int bid = blockIdx.x;
    const int tid = threadIdx.x;
    const int lane = tid & 63;
    const size_t NH = (size_t)NB * HDIM;

    int mr[4], nc[4];
    probe_mn(lane, mr, nc);

    unsigned* cnt = sync;
    unsigned* gen = sync + 1;

    f16* h0b[2] = { h16, h16 + 2 * NH };
    f16* h1b[2] = { h16 + NH, h16 + 3 * NH };
    float* h0f[2] = { hf, hf + 2 * NH };
    float* h1f[2] = { hf + NH, hf + 3 * NH };

    const int cell = bid >> 8;
    const int tb = bid & 255;

    // ---- encoder: skewed pipeline, phase i: l0(t=i) || l1(t=i-1) ----
    for (int i = 0; i <= S_LEN; i++) {
        if (cell == 0 && i < S_LEN) {
            int t = i, p = t & 1;
            gru32(tb, tid, mr, nc, red,
                  xe + (size_t)t * NB * EDIM, h0b[p], h0f[p],
                  w_eih, w_ehh, enc_bih, enc_bhh,
                  h0b[p ^ 1], h0f[p ^ 1], (f16*)nullptr, (float*)nullptr);
        } else if (cell == 1 && i >= 1) {
            int t = i - 1, p = t & 1;
            gru32(tb, tid, mr, nc, red,
                  h0b[p ^ 1], h1b[p], h1f[p],
                  w_eih + (size_t)3 * HDIM * EDIM, w_ehh + (size_t)3 * HDIM * HDIM,
                  enc_bih + 3 * HDIM, enc_bhh + 3 * HDIM,
                  h1b[p ^ 1], h1f[p ^ 1], enc16 + (size_t)t * NH, (float*)nullptr);
        }
        gbar(cnt, gen);
    }

    // ---- decoder ----
    for (int t = 0; t < S_LEN; t++) {
        int p = t & 1;
        attn_phase(bid, tid,
                   xe + (size_t)t * NB * EDIM, h0b[p], h1b[p],
                   w_attn, attn_b, enc16, xcat);
        gbar(cnt, gen);
        comb_phase(bid, tid, mr, nc, red, xcat, w_comb, comb_b, xcur);
        gbar(cnt, gen);
        gru16(bid, tid, mr, nc, red,
              xcur, h0b[p], h0f[p],
              w_dih, w_dhh, dec_bih, dec_bhh,
              h0b[p ^ 1], h0f[p ^ 1], (float*)nullptr);
        gbar(cnt, gen);
        gru16(bid, tid, mr, nc, red,
              h0b[p ^ 1], h1b[p], h1f[p],
              w_dih + (size_t)3 * HDIM * HDIM, w_dhh + (size_t)3 * HDIM * HDIM,
              dec_bih + 3 * HDIM, dec_bhh + 3 * HDIM,
              h1b[p ^ 1], h1f[p ^ 1], out + (size_t)t * NH);
        gbar(cnt, gen);
    }

    // ---- hT tail: out[S*NH .. S*NH+2NH) = hf[0 .. 2NH) (parity 0) ----
    {
        int idx = bid * 768 + tid;
        if (idx < (int)(2 * NH / 4)) {
            ((float4*)(out + (size_t)S_LEN * NH))[idx] = ((const float4*)hf)[idx];
        }
    }
}

extern "C" void kernel_launch(void* const* d_in, const int* in_sizes, int n_in,
                              void* d_out, int out_size, void* d_ws, size_t ws_size,
                              hipStream_t stream) {
    const int*   tokens   = (const int*)d_in[0];
    const float* hidden   = (const float*)d_in[1];
    const float* emb      = (const float*)d_in[2];
    const float* enc_wih  = (const float*)d_in[3];
    const float* enc_whh  = (const float*)d_in[4];
    const float* enc_bih  = (const float*)d_in[5];
    const float* enc_bhh  = (const float*)d_in[6];
    const float* dec_wih  = (const float*)d_in[7];
    const float* dec_whh  = (const float*)d_in[8];
    const float* dec_bih  = (const float*)d_in[9];
    const float* dec_bhh  = (const float*)d_in[10];
    const float* attn_w   = (const float*)d_in[11];
    const float* attn_b   = (const float*)d_in[12];
    const float* comb_w   = (const float*)d_in[13];
    const float* comb_b   = (const float*)d_in[14];
    float* out = (float*)d_out;

    const size_t NH = (size_t)NB * HDIM;             // 262144
    const size_t WSZ = (size_t)2 * 3 * HDIM * EDIM;  // 6291456

    float* hf = (float*)d_ws;                        // 4*NH f32
    f16* wp = (f16*)(hf + 4 * NH);
    f16 *w_eih = wp;  wp += WSZ;
    f16 *w_ehh = wp;  wp += WSZ;
    f16 *w_dih = wp;  wp += WSZ;
    f16 *w_dhh = wp;  wp += WSZ;
    f16 *w_comb = wp; wp += (size_t)HDIM * 2048;
    f16 *w_attn = wp; wp += (size_t)S_LEN * 3072;
    f16 *xe = wp;     wp += (size_t)S_LEN * NB * EDIM;
    f16 *enc16 = wp;  wp += (size_t)S_LEN * NH;
    f16 *h16 = wp;    wp += 4 * NH;
    f16 *xcat = wp;   wp += (size_t)NB * 2048;
    f16 *xcur = wp;   wp += NH;
    unsigned* syncp = (unsigned*)((((uintptr_t)wp) + 255) & ~(uintptr_t)255);

    k_init_sync<<<1, 1, 0, stream>>>(syncp);

    k_cvt4<<<(int)(WSZ / 4 / 256), 256, 0, stream>>>(enc_wih, w_eih, (int)(WSZ / 4));
    k_cvt4<<<(int)(WSZ / 4 / 256), 256, 0, stream>>>(enc_whh, w_ehh, (int)(WSZ / 4));
    k_cvt4<<<(int)(WSZ / 4 / 256), 256, 0, stream>>>(dec_wih, w_dih, (int)(WSZ / 4));
    k_cvt4<<<(int)(WSZ / 4 / 256), 256, 0, stream>>>(dec_whh, w_dhh, (int)(WSZ / 4));
    k_cvt4<<<(int)(HDIM * 2048 / 4 / 256), 256, 0, stream>>>(comb_w, w_comb,
                                                             HDIM * 2048 / 4);
    k_cvt4<<<(S_LEN * 3072 / 4 + 255) / 256, 256, 0, stream>>>(attn_w, w_attn,
                                                               S_LEN * 3072 / 4);
    k_embed_cvt<<<S_LEN * NB, 256, 0, stream>>>(tokens, emb, xe);
    k_cvt4<<<(int)(2 * NH / 4 / 256), 256, 0, stream>>>(hidden, h16, (int)(2 * NH / 4));
    k_copyf4<<<(int)(2 * NH / 4 / 256), 256, 0, stream>>>(hidden, hf, (int)(2 * NH / 4));

    k_mega<<<NBLK, 768, 0, stream>>>(
        xe, h16, hf,
        w_eih, w_ehh, enc_bih, enc_bhh,
        w_dih, w_dhh, dec_bih, dec_bhh,
        w_attn, attn_b, w_comb, comb_b,
        enc16, xcat, xcur, out, syncp);
}

// Round 9
// 6564.525 us; speedup vs baseline: 4.1086x; 4.1086x over previous
//
#include <hip/hip_runtime.h>
#include <hip/hip_bf16.h>

#define S_LEN 40
#define NB    256
#define EDIM  1024
#define HDIM  1024
#define NBLK  256
#define NTHR  768

typedef _Float16 f16;
typedef __attribute__((ext_vector_type(8))) _Float16 f16x8;
typedef __attribute__((ext_vector_type(4))) _Float16 f16x4;
typedef __attribute__((ext_vector_type(4))) float f32x4;

__device__ __forceinline__ float sigm(float x) {
    x = fminf(fmaxf(x, -30.f), 30.f);
    return 1.f / (1.f + __expf(-x));
}
__device__ __forceinline__ float tanh_fast(float x) {
    x = fminf(fmaxf(x, -15.f), 15.f);
    float e = __expf(2.f * x);
    return (e - 1.f) / (e + 1.f);
}

// ---- system-scope (cross-XCD, L2-bypass) memory helpers -------------------
// NOTE: asm "v" operands must be ext_vector_type (HIP float4 is a struct).
__device__ __forceinline__ void sysld_issue_b128(f16x8& v, const void* p) {
    asm volatile("global_load_dwordx4 %0, %1, off sc0 sc1" : "=v"(v) : "v"(p));
}
__device__ __forceinline__ void sysld_issue_f32(float& v, const void* p) {
    asm volatile("global_load_dword %0, %1, off sc0 sc1" : "=v"(v) : "v"(p));
}
__device__ __forceinline__ void sysld_issue_f32x4(f32x4& v, const void* p) {
    asm volatile("global_load_dwordx4 %0, %1, off sc0 sc1" : "=v"(v) : "v"(p));
}
__device__ __forceinline__ void sys_wait() {
    asm volatile("s_waitcnt vmcnt(0)" ::: "memory");
    __builtin_amdgcn_sched_barrier(0);
}
__device__ __forceinline__ void sysst_f32(float* p, float v) {
    asm volatile("global_store_dword %0, %1, off sc0 sc1" :: "v"(p), "v"(v) : "memory");
}
__device__ __forceinline__ void sysst_f32x4(float* p, f32x4 v) {
    asm volatile("global_store_dwordx4 %0, %1, off sc0 sc1" :: "v"(p), "v"(v) : "memory");
}
__device__ __forceinline__ void sysst_f16(f16* p, f16 v) {
    union { f16 f; unsigned short s; } u; u.f = v;
    unsigned int b = u.s;
    asm volatile("global_store_short %0, %1, off sc0 sc1" :: "v"(p), "v"(b) : "memory");
}

// ---- release-only grid barrier (NO acquire-invalidate: L2 stays warm) -----
__device__ __forceinline__ void gbar(unsigned* cnt, unsigned* gen) {
    asm volatile("s_waitcnt vmcnt(0)" ::: "memory");   // drain asm stores
    __syncthreads();
    if (threadIdx.x == 0) {
        unsigned g = __hip_atomic_load(gen, __ATOMIC_RELAXED, __HIP_MEMORY_SCOPE_AGENT);
        unsigned a = __hip_atomic_fetch_add(cnt, 1u, __ATOMIC_RELEASE, __HIP_MEMORY_SCOPE_AGENT);
        if (a == NBLK - 1) {
            __hip_atomic_store(cnt, 0u, __ATOMIC_RELAXED, __HIP_MEMORY_SCOPE_AGENT);
            __hip_atomic_fetch_add(gen, 1u, __ATOMIC_RELEASE, __HIP_MEMORY_SCOPE_AGENT);
        } else {
            while (__hip_atomic_load(gen, __ATOMIC_RELAXED, __HIP_MEMORY_SCOPE_AGENT) == g)
                __builtin_amdgcn_s_sleep(2);
        }
    }
    __syncthreads();
}

__global__ void k_init_sync(unsigned* s) { s[0] = 0; s[1] = 0; }

// Layout-robust probe: A[i][k]=i, B[k][j]=1/32 -> D[i][j]=i.
__device__ __forceinline__ void probe_mn(int lane, int* mrow, int* ncol) {
    f16x8 pa, pb;
#pragma unroll
    for (int e = 0; e < 8; e++) {
        pa[e] = (f16)(float)(lane & 15);
        pb[e] = (f16)0.03125f;
    }
    f32x4 pacc = {0, 0, 0, 0};
    pacc = __builtin_amdgcn_mfma_f32_16x16x32_f16(pa, pb, pacc, 0, 0, 0);
#pragma unroll
    for (int r = 0; r < 4; r++) {
        int m = (int)(pacc[r] + 0.5f);
        int cg = ((lane >> 4) << 2) + r;
        mrow[r] = m;
        ncol[r] = (m == cg) ? (lane & 15) : cg;
    }
}

// ---------------- pre-kernels ----------------------------------------------
__global__ __launch_bounds__(256) void k_cvt4(const float* __restrict__ src,
                                              f16* __restrict__ dst, int n4) {
    int i = blockIdx.x * 256 + threadIdx.x;
    if (i < n4) {
        f32x4 v = ((const f32x4*)src)[i];
        f16x4 o = {(f16)v.x, (f16)v.y, (f16)v.z, (f16)v.w};
        ((f16x4*)dst)[i] = o;
    }
}
__global__ __launch_bounds__(256) void k_copyf4(const float* __restrict__ src,
                                                float* __restrict__ dst, int n4) {
    int i = blockIdx.x * 256 + threadIdx.x;
    if (i < n4) ((f32x4*)dst)[i] = ((const f32x4*)src)[i];
}
__global__ __launch_bounds__(256) void k_embed_cvt(const int* __restrict__ tok,
                                                   const float* __restrict__ emb,
                                                   f16* __restrict__ xe) {
    int b = blockIdx.x;
    int t = threadIdx.x;
    int token = tok[b];
    f32x4 v = ((const f32x4*)(emb + (size_t)token * EDIM))[t];
    f16x4 o = {(f16)v.x, (f16)v.y, (f16)v.z, (f16)v.w};
    ((f16x4*)(xe + (size_t)b * EDIM))[t] = o;
}

// ---------------- GRU phase: 256 blocks, 32x32 tiles, 12 waves -------------
// LDS: x rows [32][2048B] at 0, h rows at 65536; red (48KB) overlaps x later.
__device__ void gru_phase(
    char* lds, int bid, int tid, const int* mr, const int* nc,
    const f16* __restrict__ xsrc, bool xsys,
    const f16* __restrict__ hsrc, const float* __restrict__ hfsrc,
    const f16* __restrict__ wih, const f16* __restrict__ whh,
    const float* __restrict__ bih, const float* __restrict__ bhh,
    f16* ho16, float* hof, f16* o216, float* o2f) {
    const int cb = (bid & 31) * 32;
    const int rb = (bid >> 5) * 32;

    // ---- stage A (x 64KB + h 64KB) into LDS, swizzled ----
    {
        constexpr int TOT = 8192;
        constexpr int IT = (TOT + NTHR - 1) / NTHR;   // 11
        f16x8 val[IT];
#pragma unroll
        for (int i = 0; i < IT; i++) {
            int c = tid + i * NTHR;
            if (c < TOT) {
                int isH = c >> 12;
                int cl = c & 4095;
                int row = cl >> 7, cc = cl & 127;
                const f16* src = (isH ? hsrc : xsrc) +
                                 (size_t)(rb + row) * 1024 + cc * 8;
                if (isH || xsys) sysld_issue_b128(val[i], src);
                else             val[i] = *(const f16x8*)src;
            }
        }
        sys_wait();
#pragma unroll
        for (int i = 0; i < IT; i++) {
            int c = tid + i * NTHR;
            if (c < TOT) {
                int isH = c >> 12;
                int cl = c & 4095;
                int row = cl >> 7, cc = cl & 127;
                *(f16x8*)(lds + isH * 65536 + row * 2048 +
                          ((cc ^ ((row & 7) << 4)) << 4)) = val[i];
            }
        }
    }
    __syncthreads();

    // ---- K loop: A from LDS, B (weights) from L2-hot global ----
    const int w = tid >> 6, lane = tid & 63;
    const int pair = w >> 1, kh = w & 1;
    const int gate = (pair >= 3) ? pair - 3 : pair;
    const int r0 = lane & 15, kk0 = (lane >> 4) * 8;
    const f16* B = ((pair < 3) ? wih : whh) + ((size_t)gate * HDIM + cb) * 1024;
    const f16* B0 = B + (size_t)r0 * 1024 + kk0 + kh * 512;
    const f16* B1 = B + (size_t)(r0 + 16) * 1024 + kk0 + kh * 512;
    const int abase = (pair < 3) ? 0 : 65536;
    const int swz0 = (r0 & 7) << 4;
    const char* a0p = lds + abase + r0 * 2048;
    const char* a1p = lds + abase + (r0 + 16) * 2048;

    f32x4 acc00 = {0,0,0,0}, acc01 = {0,0,0,0}, acc10 = {0,0,0,0}, acc11 = {0,0,0,0};
#pragma unroll 4
    for (int k = 0; k < 512; k += 32) {
        int col = kh * 512 + kk0 + k;
        int off = ((col >> 3) ^ swz0) << 4;
        f16x8 a0 = *(const f16x8*)(a0p + off);
        f16x8 a1 = *(const f16x8*)(a1p + off);
        f16x8 b0 = *(const f16x8*)(B0 + k);
        f16x8 b1 = *(const f16x8*)(B1 + k);
        acc00 = __builtin_amdgcn_mfma_f32_16x16x32_f16(a0, b0, acc00, 0, 0, 0);
        acc01 = __builtin_amdgcn_mfma_f32_16x16x32_f16(a0, b1, acc01, 0, 0, 0);
        acc10 = __builtin_amdgcn_mfma_f32_16x16x32_f16(a1, b0, acc10, 0, 0, 0);
        acc11 = __builtin_amdgcn_mfma_f32_16x16x32_f16(a1, b1, acc11, 0, 0, 0);
    }
    __syncthreads();   // all waves done reading LDS-A before red overlap

    float* red = (float*)lds;
    float* rw = red + w * 1024;
#pragma unroll
    for (int r = 0; r < 4; r++) {
        rw[mr[r] * 32 + nc[r]]             = acc00[r];
        rw[mr[r] * 32 + nc[r] + 16]        = acc01[r];
        rw[(mr[r] + 16) * 32 + nc[r]]      = acc10[r];
        rw[(mr[r] + 16) * 32 + nc[r] + 16] = acc11[r];
    }
    __syncthreads();

    // ---- epilogue ----
    {
        float hp[2];
#pragma unroll
        for (int it = 0; it < 2; it++) {
            int i = tid + it * NTHR;
            if (i < 1024) {
                int rr = i >> 5, ccn = i & 31;
                sysld_issue_f32(hp[it], hfsrc + (size_t)(rb + rr) * HDIM + cb + ccn);
            }
        }
        sys_wait();
#pragma unroll
        for (int it = 0; it < 2; it++) {
            int i = tid + it * NTHR;
            if (i < 1024) {
                int rr = i >> 5, ccn = i & 31;
                int col = cb + ccn;
                int row = rb + rr;
                float gir = red[i]         + red[1024 + i];
                float giz = red[2048 + i]  + red[3072 + i];
                float gin = red[4096 + i]  + red[5120 + i];
                float ghr = red[6144 + i]  + red[7168 + i];
                float ghz = red[8192 + i]  + red[9216 + i];
                float ghn = red[10240 + i] + red[11264 + i];
                float r = sigm(gir + bih[col] + ghr + bhh[col]);
                float z = sigm(giz + bih[HDIM + col] + ghz + bhh[HDIM + col]);
                float n = tanh_fast(gin + bih[2 * HDIM + col] +
                                    r * (ghn + bhh[2 * HDIM + col]));
                float hn2 = (1.f - z) * n + z * hp[it];
                size_t idx = (size_t)row * HDIM + col;
                sysst_f16(ho16 + idx, (f16)hn2);
                sysst_f32(hof + idx, hn2);
                if (o216) sysst_f16(o216 + idx, (f16)hn2);
                if (o2f)  sysst_f32(o2f + idx, hn2);
            }
        }
    }
}

// ---------------- attention phase: 256 blocks = 256 batch rows -------------
__device__ void attn_phase(
    char* lds, int bid, int tid,
    const f16* __restrict__ xe_t, const f16* __restrict__ h0,
    const f16* __restrict__ h1,
    const f16* __restrict__ attn_w, const float* __restrict__ attn_b,
    const f16* __restrict__ enc16, f16* __restrict__ appl) {
    float* logit = (float*)(lds + 131072);
    float* awls  = logit + 64;
    const int n = bid;
    const int w = tid >> 6, lane = tid & 63;

    // ---- stage enc rows (80KB) + x/h0/h1 rows (6KB) ----
    {
        constexpr int TOT = 5504;   // 5120 enc + 384 rows
        constexpr int IT = (TOT + NTHR - 1) / NTHR;  // 8
        f16x8 val[IT];
#pragma unroll
        for (int i = 0; i < IT; i++) {
            int c = tid + i * NTHR;
            if (c < TOT) {
                if (c < 5120) {
                    int s = c >> 7, cc = c & 127;
                    sysld_issue_b128(val[i], enc16 + ((size_t)s * NB + n) * 1024 + cc * 8);
                } else {
                    int r = c - 5120;
                    if (r < 128) {
                        val[i] = *(const f16x8*)(xe_t + (size_t)n * 1024 + r * 8);
                    } else if (r < 256) {
                        sysld_issue_b128(val[i], h0 + (size_t)n * 1024 + (r - 128) * 8);
                    } else {
                        sysld_issue_b128(val[i], h1 + (size_t)n * 1024 + (r - 256) * 8);
                    }
                }
            }
        }
        sys_wait();
#pragma unroll
        for (int i = 0; i < IT; i++) {
            int c = tid + i * NTHR;
            if (c < TOT) {
                if (c < 5120) *(f16x8*)(lds + c * 16) = val[i];
                else          *(f16x8*)(lds + 81920 + (c - 5120) * 16) = val[i];
            }
        }
    }
    __syncthreads();

    // ---- logits: waves 0..9 x 4 rows ----
    if (w < 10) {
#pragma unroll
        for (int si = 0; si < 4; si++) {
            int s = w * 4 + si;
            const f16* wrow = attn_w + (size_t)s * 3072;
            float acc = 0.f;
#pragma unroll
            for (int jj = 0; jj < 6; jj++) {
                int j = lane + jj * 64;
                f16x8 a = *(const f16x8*)(lds + 81920 + j * 16);
                f16x8 b = *(const f16x8*)(wrow + j * 8);
#pragma unroll
                for (int e = 0; e < 8; e++)
                    acc = fmaf((float)a[e], (float)b[e], acc);
            }
            for (int o = 32; o; o >>= 1) acc += __shfl_down(acc, o);
            if (lane == 0) logit[s] = acc + attn_b[s];
        }
    }
    __syncthreads();

    if (w == 0) {
        float v = (lane < S_LEN) ? logit[lane] : -1e30f;
        float m = v;
        for (int o = 32; o; o >>= 1) m = fmaxf(m, __shfl_xor(m, o));
        float e = (lane < S_LEN) ? __expf(v - m) : 0.f;
        float sum = e;
        for (int o = 32; o; o >>= 1) sum += __shfl_xor(sum, o);
        if (lane < S_LEN) awls[lane] = e / sum;
    }
    __syncthreads();

    // ---- context -> appl[n][:] ----
    for (int col = tid; col < 1024; col += NTHR) {
        float acc = 0.f;
#pragma unroll
        for (int s = 0; s < S_LEN; s++)
            acc = fmaf(awls[s], (float)*(const f16*)(lds + s * 2048 + col * 2), acc);
        sysst_f16(appl + (size_t)n * 1024 + col, (f16)acc);
    }
}

// ---------------- comb phase: 256 blocks, 32x32 tiles, 12-way K split ------
__device__ void comb_phase(
    char* lds, int bid, int tid, const int* mr, const int* nc,
    const f16* __restrict__ xe_t, const f16* __restrict__ appl,
    const f16* __restrict__ Bw, const float* __restrict__ bias,
    f16* __restrict__ Cout) {
    const int cb = (bid & 31) * 32;
    const int rb = (bid >> 5) * 32;

    // ---- stage A = [xe_t | appl] rows: 32 x 4096B = 128KB ----
    {
        constexpr int TOT = 8192;
        constexpr int IT = (TOT + NTHR - 1) / NTHR;   // 11
        f16x8 val[IT];
#pragma unroll
        for (int i = 0; i < IT; i++) {
            int c = tid + i * NTHR;
            if (c < TOT) {
                int row = c >> 8, cc = c & 255;
                if (cc < 128)
                    sysld_issue_b128(val[i], xe_t + (size_t)(rb + row) * 1024 + cc * 8);
                else
                    sysld_issue_b128(val[i], appl + (size_t)(rb + row) * 1024 + (cc - 128) * 8);
            }
        }
        sys_wait();
#pragma unroll
        for (int i = 0; i < IT; i++) {
            int c = tid + i * NTHR;
            if (c < TOT) {
                int row = c >> 8, cc = c & 255;
                *(f16x8*)(lds + row * 4096 + ((cc ^ ((row & 7) << 4)) << 4)) = val[i];
            }
        }
    }
    __syncthreads();

    const int w = tid >> 6, lane = tid & 63;
    const int r0 = lane & 15, kk0 = (lane >> 4) * 8;
    const int c0 = (w * 64) / 12, c1 = ((w + 1) * 64) / 12;
    const f16* B0 = Bw + (size_t)(cb + r0) * 2048 + kk0;
    const f16* B1 = Bw + (size_t)(cb + r0 + 16) * 2048 + kk0;
    const int swz0 = (r0 & 7) << 4;
    const char* a0p = lds + r0 * 4096;
    const char* a1p = lds + (r0 + 16) * 4096;

    f32x4 acc00 = {0,0,0,0}, acc01 = {0,0,0,0}, acc10 = {0,0,0,0}, acc11 = {0,0,0,0};
    for (int c = c0; c < c1; c++) {
        int col = c * 32 + kk0;
        int off = ((col >> 3) ^ swz0) << 4;
        f16x8 a0 = *(const f16x8*)(a0p + off);
        f16x8 a1 = *(const f16x8*)(a1p + off);
        f16x8 b0 = *(const f16x8*)(B0 + c * 32);
        f16x8 b1 = *(const f16x8*)(B1 + c * 32);
        acc00 = __builtin_amdgcn_mfma_f32_16x16x32_f16(a0, b0, acc00, 0, 0, 0);
        acc01 = __builtin_amdgcn_mfma_f32_16x16x32_f16(a0, b1, acc01, 0, 0, 0);
        acc10 = __builtin_amdgcn_mfma_f32_16x16x32_f16(a1, b0, acc10, 0, 0, 0);
        acc11 = __builtin_amdgcn_mfma_f32_16x16x32_f16(a1, b1, acc11, 0, 0, 0);
    }
    __syncthreads();

    float* red = (float*)lds;
    float* rw = red + w * 1024;
#pragma unroll
    for (int r = 0; r < 4; r++) {
        rw[mr[r] * 32 + nc[r]]             = acc00[r];
        rw[mr[r] * 32 + nc[r] + 16]        = acc01[r];
        rw[(mr[r] + 16) * 32 + nc[r]]      = acc10[r];
        rw[(mr[r] + 16) * 32 + nc[r] + 16] = acc11[r];
    }
    __syncthreads();

#pragma unroll
    for (int it = 0; it < 2; it++) {
        int i = tid + it * NTHR;
        if (i < 1024) {
            float s = 0.f;
#pragma unroll
            for (int p = 0; p < 12; p++) s += red[p * 1024 + i];
            int rr = i >> 5, ccn = i & 31;
            s += bias[cb + ccn];
            s = fmaxf(s, 0.f);
            sysst_f16(Cout + (size_t)(rb + rr) * 1024 + cb + ccn, (f16)s);
        }
    }
}

// ---------------- the mega kernel ------------------------------------------
__global__ __launch_bounds__(NTHR, 3) void k_mega(
    const f16* __restrict__ xe,
    f16* h16, float* hf,
    const f16* __restrict__ w_eih, const f16* __restrict__ w_ehh,
    const float* __restrict__ enc_bih, const float* __restrict__ enc_bhh,
    const f16* __restrict__ w_dih, const f16* __restrict__ w_dhh,
    const float* __restrict__ dec_bih, const float* __restrict__ dec_bhh,
    const f16* __restrict__ w_attn, const float* __restrict__ attn_b,
    const f16* __restrict__ w_comb, const float* __restrict__ comb_b,
    f16* enc16, f16* appl, f16* xcur,
    float* out, unsigned* sync) {
    __shared__ char smem[131584];
    char* lds = smem;
    const int bid = blockIdx.x;
    const int tid = threadIdx.x;
    const int lane = tid & 63;
    const size_t NH = (size_t)NB * HDIM;

    int mr[4], nc[4];
    probe_mn(lane, mr, nc);

    unsigned* cnt = sync;
    unsigned* gen = sync + 1;

    f16* h0b[2] = { h16, h16 + 2 * NH };
    f16* h1b[2] = { h16 + NH, h16 + 3 * NH };
    float* h0f[2] = { hf, hf + 2 * NH };
    float* h1f[2] = { hf + NH, hf + 3 * NH };

    // ---- encoder ----
    for (int t = 0; t < S_LEN; t++) {
        int p = t & 1;
        gru_phase(lds, bid, tid, mr, nc,
                  xe + (size_t)t * NB * EDIM, false,
                  h0b[p], h0f[p],
                  w_eih, w_ehh, enc_bih, enc_bhh,
                  h0b[p ^ 1], h0f[p ^ 1], (f16*)nullptr, (float*)nullptr);
        gbar(cnt, gen);
        gru_phase(lds, bid, tid, mr, nc,
                  h0b[p ^ 1], true,
                  h1b[p], h1f[p],
                  w_eih + (size_t)3 * HDIM * EDIM, w_ehh + (size_t)3 * HDIM * HDIM,
                  enc_bih + 3 * HDIM, enc_bhh + 3 * HDIM,
                  h1b[p ^ 1], h1f[p ^ 1], enc16 + (size_t)t * NH, (float*)nullptr);
        gbar(cnt, gen);
    }

    // ---- decoder ----
    for (int t = 0; t < S_LEN; t++) {
        int p = t & 1;
        attn_phase(lds, bid, tid,
                   xe + (size_t)t * NB * EDIM, h0b[p], h1b[p],
                   w_attn, attn_b, enc16, appl);
        gbar(cnt, gen);
        comb_phase(lds, bid, tid, mr, nc,
                   xe + (size_t)t * NB * EDIM, appl, w_comb, comb_b, xcur);
        gbar(cnt, gen);
        gru_phase(lds, bid, tid, mr, nc,
                  xcur, true,
                  h0b[p], h0f[p],
                  w_dih, w_dhh, dec_bih, dec_bhh,
                  h0b[p ^ 1], h0f[p ^ 1], (f16*)nullptr, (float*)nullptr);
        gbar(cnt, gen);
        gru_phase(lds, bid, tid, mr, nc,
                  h0b[p ^ 1], true,
                  h1b[p], h1f[p],
                  w_dih + (size_t)3 * HDIM * HDIM, w_dhh + (size_t)3 * HDIM * HDIM,
                  dec_bih + 3 * HDIM, dec_bhh + 3 * HDIM,
                  h1b[p ^ 1], h1f[p ^ 1], (f16*)nullptr, out + (size_t)t * NH);
        gbar(cnt, gen);
    }

    // ---- hT tail: out[S*NH .. S*NH+2NH) = hf[0 .. 2NH) ----
    if (tid < 512) {
        size_t idx = (size_t)bid * 512 + tid;
        f32x4 v;
        sysld_issue_f32x4(v, hf + idx * 4);
        sys_wait();
        sysst_f32x4(out + (size_t)S_LEN * NH + idx * 4, v);
    }
}

extern "C" void kernel_launch(void* const* d_in, const int* in_sizes, int n_in,
                              void* d_out, int out_size, void* d_ws, size_t ws_size,
                              hipStream_t stream) {
    const int*   tokens   = (const int*)d_in[0];
    const float* hidden   = (const float*)d_in[1];
    const float* emb      = (const float*)d_in[2];
    const float* enc_wih  = (const float*)d_in[3];
    const float* enc_whh  = (const float*)d_in[4];
    const float* enc_bih  = (const float*)d_in[5];
    const float* enc_bhh  = (const float*)d_in[6];
    const float* dec_wih  = (const float*)d_in[7];
    const float* dec_whh  = (const float*)d_in[8];
    const float* dec_bih  = (const float*)d_in[9];
    const float* dec_bhh  = (const float*)d_in[10];
    const float* attn_w   = (const float*)d_in[11];
    const float* attn_b   = (const float*)d_in[12];
    const float* comb_w   = (const float*)d_in[13];
    const float* comb_b   = (const float*)d_in[14];
    float* out = (float*)d_out;

    const size_t NH = (size_t)NB * HDIM;             // 262144
    const size_t WSZ = (size_t)2 * 3 * HDIM * EDIM;  // 6291456

    float* hf = (float*)d_ws;                        // 4*NH f32
    f16* wp = (f16*)(hf + 4 * NH);
    f16 *w_eih = wp;  wp += WSZ;
    f16 *w_ehh = wp;  wp += WSZ;
    f16 *w_dih = wp;  wp += WSZ;
    f16 *w_dhh = wp;  wp += WSZ;
    f16 *w_comb = wp; wp += (size_t)HDIM * 2048;
    f16 *w_attn = wp; wp += (size_t)S_LEN * 3072;
    f16 *xe = wp;     wp += (size_t)S_LEN * NB * EDIM;
    f16 *enc16 = wp;  wp += (size_t)S_LEN * NH;
    f16 *h16 = wp;    wp += 4 * NH;
    f16 *appl = wp;   wp += NH;
    f16 *xcur = wp;   wp += NH;
    unsigned* syncp = (unsigned*)((((uintptr_t)wp) + 255) & ~(uintptr_t)255);

    k_init_sync<<<1, 1, 0, stream>>>(syncp);

    k_cvt4<<<(int)(WSZ / 4 / 256), 256, 0, stream>>>(enc_wih, w_eih, (int)(WSZ / 4));
    k_cvt4<<<(int)(WSZ / 4 / 256), 256, 0, stream>>>(enc_whh, w_ehh, (int)(WSZ / 4));
    k_cvt4<<<(int)(WSZ / 4 / 256), 256, 0, stream>>>(dec_wih, w_dih, (int)(WSZ / 4));
    k_cvt4<<<(int)(WSZ / 4 / 256), 256, 0, stream>>>(dec_whh, w_dhh, (int)(WSZ / 4));
    k_cvt4<<<(int)(HDIM * 2048 / 4 / 256), 256, 0, stream>>>(comb_w, w_comb,
                                                             HDIM * 2048 / 4);
    k_cvt4<<<(S_LEN * 3072 / 4 + 255) / 256, 256, 0, stream>>>(attn_w, w_attn,
                                                               S_LEN * 3072 / 4);
    k_embed_cvt<<<S_LEN * NB, 256, 0, stream>>>(tokens, emb, xe);
    k_cvt4<<<(int)(2 * NH / 4 / 256), 256, 0, stream>>>(hidden, h16, (int)(2 * NH / 4));
    k_copyf4<<<(int)(2 * NH / 4 / 256), 256, 0, stream>>>(hidden, hf, (int)(2 * NH / 4));

    k_mega<<<NBLK, NTHR, 0, stream>>>(
        xe, h16, hf,
        w_eih, w_ehh, enc_bih, enc_bhh,
        w_dih, w_dhh, dec_bih, dec_bhh,
        w_attn, attn_b, w_comb, comb_b,
        enc16, appl, xcur, out, syncp);
}

// Round 10
// 6494.605 us; speedup vs baseline: 4.1528x; 1.0108x over previous
//
#include <hip/hip_runtime.h>
#include <hip/hip_bf16.h>

#define S_LEN 40
#define NB    256
#define EDIM  1024
#define HDIM  1024
#define NBLK  256
#define NTHR  768

typedef _Float16 f16;
typedef __attribute__((ext_vector_type(8))) _Float16 f16x8;
typedef __attribute__((ext_vector_type(4))) _Float16 f16x4;
typedef __attribute__((ext_vector_type(4))) float f32x4;

__device__ __forceinline__ float sigm(float x) {
    x = fminf(fmaxf(x, -30.f), 30.f);
    return 1.f / (1.f + __expf(-x));
}
__device__ __forceinline__ float tanh_fast(float x) {
    x = fminf(fmaxf(x, -15.f), 15.f);
    float e = __expf(2.f * x);
    return (e - 1.f) / (e + 1.f);
}

// ---- system-scope (cross-XCD, L2-bypass) memory helpers -------------------
__device__ __forceinline__ void sysld_issue_b128(f16x8& v, const void* p) {
    asm volatile("global_load_dwordx4 %0, %1, off sc0 sc1" : "=v"(v) : "v"(p));
}
__device__ __forceinline__ void sysld_issue_f32(float& v, const void* p) {
    asm volatile("global_load_dword %0, %1, off sc0 sc1" : "=v"(v) : "v"(p));
}
__device__ __forceinline__ void sysld_issue_f32x4(f32x4& v, const void* p) {
    asm volatile("global_load_dwordx4 %0, %1, off sc0 sc1" : "=v"(v) : "v"(p));
}
__device__ __forceinline__ void sys_wait() {
    asm volatile("s_waitcnt vmcnt(0)" ::: "memory");
    __builtin_amdgcn_sched_barrier(0);
}
__device__ __forceinline__ void sysst_f32(float* p, float v) {
    asm volatile("global_store_dword %0, %1, off sc0 sc1" :: "v"(p), "v"(v) : "memory");
}
__device__ __forceinline__ void sysst_f32x4(float* p, f32x4 v) {
    asm volatile("global_store_dwordx4 %0, %1, off sc0 sc1" :: "v"(p), "v"(v) : "memory");
}
__device__ __forceinline__ void sysst_f16(f16* p, f16 v) {
    union { f16 f; unsigned short s; } u; u.f = v;
    unsigned int b = u.s;
    asm volatile("global_store_short %0, %1, off sc0 sc1" :: "v"(p), "v"(b) : "memory");
}

// ---- release-only grid barrier (NO acquire-invalidate: L2 stays warm) -----
__device__ __forceinline__ void gbar(unsigned* cnt, unsigned* gen) {
    asm volatile("s_waitcnt vmcnt(0)" ::: "memory");   // drain asm stores
    __syncthreads();
    if (threadIdx.x == 0) {
        unsigned g = __hip_atomic_load(gen, __ATOMIC_RELAXED, __HIP_MEMORY_SCOPE_AGENT);
        unsigned a = __hip_atomic_fetch_add(cnt, 1u, __ATOMIC_RELEASE, __HIP_MEMORY_SCOPE_AGENT);
        if (a == NBLK - 1) {
            __hip_atomic_store(cnt, 0u, __ATOMIC_RELAXED, __HIP_MEMORY_SCOPE_AGENT);
            __hip_atomic_fetch_add(gen, 1u, __ATOMIC_RELEASE, __HIP_MEMORY_SCOPE_AGENT);
        } else {
            while (__hip_atomic_load(gen, __ATOMIC_RELAXED, __HIP_MEMORY_SCOPE_AGENT) == g)
                __builtin_amdgcn_s_sleep(2);
        }
    }
    __syncthreads();
}

__global__ void k_init_sync(unsigned* s) { s[0] = 0; s[1] = 0; }

// Layout-robust probe: A[i][k]=i, B[k][j]=1/32 -> D[i][j]=i.
__device__ __forceinline__ void probe_mn(int lane, int* mrow, int* ncol) {
    f16x8 pa, pb;
#pragma unroll
    for (int e = 0; e < 8; e++) {
        pa[e] = (f16)(float)(lane & 15);
        pb[e] = (f16)0.03125f;
    }
    f32x4 pacc = {0, 0, 0, 0};
    pacc = __builtin_amdgcn_mfma_f32_16x16x32_f16(pa, pb, pacc, 0, 0, 0);
#pragma unroll
    for (int r = 0; r < 4; r++) {
        int m = (int)(pacc[r] + 0.5f);
        int cg = ((lane >> 4) << 2) + r;
        mrow[r] = m;
        ncol[r] = (m == cg) ? (lane & 15) : cg;
    }
}

// ---------------- pre-kernels ----------------------------------------------
__global__ __launch_bounds__(256) void k_cvt4(const float* __restrict__ src,
                                              f16* __restrict__ dst, int n4) {
    int i = blockIdx.x * 256 + threadIdx.x;
    if (i < n4) {
        f32x4 v = ((const f32x4*)src)[i];
        f16x4 o = {(f16)v.x, (f16)v.y, (f16)v.z, (f16)v.w};
        ((f16x4*)dst)[i] = o;
    }
}
__global__ __launch_bounds__(256) void k_copyf4(const float* __restrict__ src,
                                                float* __restrict__ dst, int n4) {
    int i = blockIdx.x * 256 + threadIdx.x;
    if (i < n4) ((f32x4*)dst)[i] = ((const f32x4*)src)[i];
}
__global__ __launch_bounds__(256) void k_embed_cvt(const int* __restrict__ tok,
                                                   const float* __restrict__ emb,
                                                   f16* __restrict__ xe) {
    int b = blockIdx.x;
    int t = threadIdx.x;
    int token = tok[b];
    f32x4 v = ((const f32x4*)(emb + (size_t)token * EDIM))[t];
    f16x4 o = {(f16)v.x, (f16)v.y, (f16)v.z, (f16)v.w};
    ((f16x4*)(xe + (size_t)b * EDIM))[t] = o;
}

// ---------------- GRU phase: 256 blocks, 32x32 tiles, 12 waves -------------
// LDS: x rows [32][2048B] at 0, h rows at 65536; red (48KB) overlaps x later.
// Bank-correct swizzle: 16B-slot index XORed with (row&7)  (byte bits 4-6).
__device__ void gru_phase(
    char* lds, int bid, int tid, const int* mr, const int* nc,
    const f16* __restrict__ xsrc, bool xsys,
    const f16* __restrict__ hsrc, const float* __restrict__ hfsrc,
    const f16* __restrict__ wih, const f16* __restrict__ whh,
    const float* __restrict__ bih, const float* __restrict__ bhh,
    f16* ho16, float* hof, f16* o216, float* o2f) {
    const int cb = (bid & 31) * 32;
    const int rb = (bid >> 5) * 32;

    // ---- stage A (x 64KB + h 64KB) into LDS, swizzled ----
    {
        constexpr int TOT = 8192;
        constexpr int IT = (TOT + NTHR - 1) / NTHR;   // 11
        f16x8 val[IT];
#pragma unroll
        for (int i = 0; i < IT; i++) {
            int c = tid + i * NTHR;
            if (c < TOT) {
                int isH = c >> 12;
                int cl = c & 4095;
                int row = cl >> 7, cc = cl & 127;
                const f16* src = (isH ? hsrc : xsrc) +
                                 (size_t)(rb + row) * 1024 + cc * 8;
                if (isH || xsys) sysld_issue_b128(val[i], src);
                else             val[i] = *(const f16x8*)src;
            }
        }
        sys_wait();
#pragma unroll
        for (int i = 0; i < IT; i++) {
            int c = tid + i * NTHR;
            if (c < TOT) {
                int isH = c >> 12;
                int cl = c & 4095;
                int row = cl >> 7, cc = cl & 127;
                *(f16x8*)(lds + isH * 65536 + row * 2048 +
                          ((cc ^ (row & 7)) << 4)) = val[i];
            }
        }
    }
    __syncthreads();

    // ---- K loop: A from LDS, B (weights) from L2-hot global ----
    const int w = tid >> 6, lane = tid & 63;
    const int pair = w >> 1, kh = w & 1;
    const int gate = (pair >= 3) ? pair - 3 : pair;
    const int r0 = lane & 15, kk0 = (lane >> 4) * 8;
    const f16* B = ((pair < 3) ? wih : whh) + ((size_t)gate * HDIM + cb) * 1024;
    const f16* B0 = B + (size_t)r0 * 1024 + kk0 + kh * 512;
    const f16* B1 = B + (size_t)(r0 + 16) * 1024 + kk0 + kh * 512;
    const int abase = (pair < 3) ? 0 : 65536;
    const int swz = r0 & 7;     // (r0+16)&7 == r0&7
    const char* a0p = lds + abase + r0 * 2048;
    const char* a1p = lds + abase + (r0 + 16) * 2048;

    f32x4 acc00 = {0,0,0,0}, acc01 = {0,0,0,0}, acc10 = {0,0,0,0}, acc11 = {0,0,0,0};
#pragma unroll 4
    for (int k = 0; k < 512; k += 32) {
        int g = (kh * 512 + kk0 + k) >> 3;
        int off = (g ^ swz) << 4;
        f16x8 a0 = *(const f16x8*)(a0p + off);
        f16x8 a1 = *(const f16x8*)(a1p + off);
        f16x8 b0 = *(const f16x8*)(B0 + k);
        f16x8 b1 = *(const f16x8*)(B1 + k);
        acc00 = __builtin_amdgcn_mfma_f32_16x16x32_f16(a0, b0, acc00, 0, 0, 0);
        acc01 = __builtin_amdgcn_mfma_f32_16x16x32_f16(a0, b1, acc01, 0, 0, 0);
        acc10 = __builtin_amdgcn_mfma_f32_16x16x32_f16(a1, b0, acc10, 0, 0, 0);
        acc11 = __builtin_amdgcn_mfma_f32_16x16x32_f16(a1, b1, acc11, 0, 0, 0);
    }
    __syncthreads();   // all waves done reading LDS-A before red overlap

    float* red = (float*)lds;
    float* rw = red + w * 1024;
#pragma unroll
    for (int r = 0; r < 4; r++) {
        rw[mr[r] * 32 + nc[r]]             = acc00[r];
        rw[mr[r] * 32 + nc[r] + 16]        = acc01[r];
        rw[(mr[r] + 16) * 32 + nc[r]]      = acc10[r];
        rw[(mr[r] + 16) * 32 + nc[r] + 16] = acc11[r];
    }
    __syncthreads();

    // ---- epilogue ----
    {
        float hp[2];
#pragma unroll
        for (int it = 0; it < 2; it++) {
            int i = tid + it * NTHR;
            if (i < 1024) {
                int rr = i >> 5, ccn = i & 31;
                sysld_issue_f32(hp[it], hfsrc + (size_t)(rb + rr) * HDIM + cb + ccn);
            }
        }
        sys_wait();
#pragma unroll
        for (int it = 0; it < 2; it++) {
            int i = tid + it * NTHR;
            if (i < 1024) {
                int rr = i >> 5, ccn = i & 31;
                int col = cb + ccn;
                int row = rb + rr;
                float gir = red[i]         + red[1024 + i];
                float giz = red[2048 + i]  + red[3072 + i];
                float gin = red[4096 + i]  + red[5120 + i];
                float ghr = red[6144 + i]  + red[7168 + i];
                float ghz = red[8192 + i]  + red[9216 + i];
                float ghn = red[10240 + i] + red[11264 + i];
                float r = sigm(gir + bih[col] + ghr + bhh[col]);
                float z = sigm(giz + bih[HDIM + col] + ghz + bhh[HDIM + col]);
                float n = tanh_fast(gin + bih[2 * HDIM + col] +
                                    r * (ghn + bhh[2 * HDIM + col]));
                float hn2 = (1.f - z) * n + z * hp[it];
                size_t idx = (size_t)row * HDIM + col;
                sysst_f16(ho16 + idx, (f16)hn2);
                sysst_f32(hof + idx, hn2);
                if (o216) sysst_f16(o216 + idx, (f16)hn2);
                if (o2f)  sysst_f32(o2f + idx, hn2);
            }
        }
    }
}

// ---------------- attention phase: 256 blocks = 256 batch rows -------------
__device__ void attn_phase(
    char* lds, int bid, int tid,
    const f16* __restrict__ xe_t, const f16* __restrict__ h0,
    const f16* __restrict__ h1,
    const f16* __restrict__ attn_w, const float* __restrict__ attn_b,
    const f16* __restrict__ enc16, f16* __restrict__ appl) {
    float* logit = (float*)(lds + 131072);
    float* awls  = logit + 64;
    const int n = bid;
    const int w = tid >> 6, lane = tid & 63;

    // ---- stage enc rows (80KB, CACHED: read-only during decoder) +
    //      x (cached) / h0,h1 (bypass) rows (6KB) ----
    {
        constexpr int TOT = 5504;   // 5120 enc + 384 rows
        constexpr int IT = (TOT + NTHR - 1) / NTHR;  // 8
        f16x8 val[IT];
#pragma unroll
        for (int i = 0; i < IT; i++) {
            int c = tid + i * NTHR;
            if (c < TOT) {
                if (c < 5120) {
                    int s = c >> 7, cc = c & 127;
                    val[i] = *(const f16x8*)(enc16 + ((size_t)s * NB + n) * 1024 + cc * 8);
                } else {
                    int r = c - 5120;
                    if (r < 128) {
                        val[i] = *(const f16x8*)(xe_t + (size_t)n * 1024 + r * 8);
                    } else if (r < 256) {
                        sysld_issue_b128(val[i], h0 + (size_t)n * 1024 + (r - 128) * 8);
                    } else {
                        sysld_issue_b128(val[i], h1 + (size_t)n * 1024 + (r - 256) * 8);
                    }
                }
            }
        }
        sys_wait();
#pragma unroll
        for (int i = 0; i < IT; i++) {
            int c = tid + i * NTHR;
            if (c < TOT) {
                if (c < 5120) *(f16x8*)(lds + c * 16) = val[i];
                else          *(f16x8*)(lds + 81920 + (c - 5120) * 16) = val[i];
            }
        }
    }
    __syncthreads();

    // ---- logits: waves 0..9 x 4 rows ----
    if (w < 10) {
#pragma unroll
        for (int si = 0; si < 4; si++) {
            int s = w * 4 + si;
            const f16* wrow = attn_w + (size_t)s * 3072;
            float acc = 0.f;
#pragma unroll
            for (int jj = 0; jj < 6; jj++) {
                int j = lane + jj * 64;
                f16x8 a = *(const f16x8*)(lds + 81920 + j * 16);
                f16x8 b = *(const f16x8*)(wrow + j * 8);
#pragma unroll
                for (int e = 0; e < 8; e++)
                    acc = fmaf((float)a[e], (float)b[e], acc);
            }
            for (int o = 32; o; o >>= 1) acc += __shfl_down(acc, o);
            if (lane == 0) logit[s] = acc + attn_b[s];
        }
    }
    __syncthreads();

    if (w == 0) {
        float v = (lane < S_LEN) ? logit[lane] : -1e30f;
        float m = v;
        for (int o = 32; o; o >>= 1) m = fmaxf(m, __shfl_xor(m, o));
        float e = (lane < S_LEN) ? __expf(v - m) : 0.f;
        float sum = e;
        for (int o = 32; o; o >>= 1) sum += __shfl_xor(sum, o);
        if (lane < S_LEN) awls[lane] = e / sum;
    }
    __syncthreads();

    // ---- context -> appl[n][:] ----
    for (int col = tid; col < 1024; col += NTHR) {
        float acc = 0.f;
#pragma unroll
        for (int s = 0; s < S_LEN; s++)
            acc = fmaf(awls[s], (float)*(const f16*)(lds + s * 2048 + col * 2), acc);
        sysst_f16(appl + (size_t)n * 1024 + col, (f16)acc);
    }
}

// ---------------- comb phase: 256 blocks, 32x32 tiles, 12-way K split ------
__device__ void comb_phase(
    char* lds, int bid, int tid, const int* mr, const int* nc,
    const f16* __restrict__ xe_t, const f16* __restrict__ appl,
    const f16* __restrict__ Bw, const float* __restrict__ bias,
    f16* __restrict__ Cout) {
    const int cb = (bid & 31) * 32;
    const int rb = (bid >> 5) * 32;

    // ---- stage A = [xe_t (cached) | appl (bypass)] rows: 32 x 4096B ----
    {
        constexpr int TOT = 8192;
        constexpr int IT = (TOT + NTHR - 1) / NTHR;   // 11
        f16x8 val[IT];
#pragma unroll
        for (int i = 0; i < IT; i++) {
            int c = tid + i * NTHR;
            if (c < TOT) {
                int row = c >> 8, cc = c & 255;
                if (cc < 128)
                    val[i] = *(const f16x8*)(xe_t + (size_t)(rb + row) * 1024 + cc * 8);
                else
                    sysld_issue_b128(val[i], appl + (size_t)(rb + row) * 1024 + (cc - 128) * 8);
            }
        }
        sys_wait();
#pragma unroll
        for (int i = 0; i < IT; i++) {
            int c = tid + i * NTHR;
            if (c < TOT) {
                int row = c >> 8, cc = c & 255;
                *(f16x8*)(lds + row * 4096 + ((cc ^ (row & 7)) << 4)) = val[i];
            }
        }
    }
    __syncthreads();

    const int w = tid >> 6, lane = tid & 63;
    const int r0 = lane & 15, kk0 = (lane >> 4) * 8;
    const int c0 = (w * 64) / 12, c1 = ((w + 1) * 64) / 12;
    const f16* B0 = Bw + (size_t)(cb + r0) * 2048 + kk0;
    const f16* B1 = Bw + (size_t)(cb + r0 + 16) * 2048 + kk0;
    const int swz = r0 & 7;
    const char* a0p = lds + r0 * 4096;
    const char* a1p = lds + (r0 + 16) * 4096;

    f32x4 acc00 = {0,0,0,0}, acc01 = {0,0,0,0}, acc10 = {0,0,0,0}, acc11 = {0,0,0,0};
    for (int c = c0; c < c1; c++) {
        int g = (c * 32 + kk0) >> 3;
        int off = (g ^ swz) << 4;
        f16x8 a0 = *(const f16x8*)(a0p + off);
        f16x8 a1 = *(const f16x8*)(a1p + off);
        f16x8 b0 = *(const f16x8*)(B0 + c * 32);
        f16x8 b1 = *(const f16x8*)(B1 + c * 32);
        acc00 = __builtin_amdgcn_mfma_f32_16x16x32_f16(a0, b0, acc00, 0, 0, 0);
        acc01 = __builtin_amdgcn_mfma_f32_16x16x32_f16(a0, b1, acc01, 0, 0, 0);
        acc10 = __builtin_amdgcn_mfma_f32_16x16x32_f16(a1, b0, acc10, 0, 0, 0);
        acc11 = __builtin_amdgcn_mfma_f32_16x16x32_f16(a1, b1, acc11, 0, 0, 0);
    }
    __syncthreads();

    float* red = (float*)lds;
    float* rw = red + w * 1024;
#pragma unroll
    for (int r = 0; r < 4; r++) {
        rw[mr[r] * 32 + nc[r]]             = acc00[r];
        rw[mr[r] * 32 + nc[r] + 16]        = acc01[r];
        rw[(mr[r] + 16) * 32 + nc[r]]      = acc10[r];
        rw[(mr[r] + 16) * 32 + nc[r] + 16] = acc11[r];
    }
    __syncthreads();

#pragma unroll
    for (int it = 0; it < 2; it++) {
        int i = tid + it * NTHR;
        if (i < 1024) {
            float s = 0.f;
#pragma unroll
            for (int p = 0; p < 12; p++) s += red[p * 1024 + i];
            int rr = i >> 5, ccn = i & 31;
            s += bias[cb + ccn];
            s = fmaxf(s, 0.f);
            sysst_f16(Cout + (size_t)(rb + rr) * 1024 + cb + ccn, (f16)s);
        }
    }
}

// ---------------- the mega kernel ------------------------------------------
__global__ __launch_bounds__(NTHR, 3) void k_mega(
    const f16* __restrict__ xe,
    f16* h16, float* hf,
    const f16* __restrict__ w_eih, const f16* __restrict__ w_ehh,
    const float* __restrict__ enc_bih, const float* __restrict__ enc_bhh,
    const f16* __restrict__ w_dih, const f16* __restrict__ w_dhh,
    const float* __restrict__ dec_bih, const float* __restrict__ dec_bhh,
    const f16* __restrict__ w_attn, const float* __restrict__ attn_b,
    const f16* __restrict__ w_comb, const float* __restrict__ comb_b,
    f16* enc16, f16* appl, f16* xcur,
    float* out, unsigned* sync) {
    __shared__ char smem[131584];
    char* lds = smem;
    const int bid = blockIdx.x;
    const int tid = threadIdx.x;
    const int lane = tid & 63;
    const size_t NH = (size_t)NB * HDIM;

    int mr[4], nc[4];
    probe_mn(lane, mr, nc);

    unsigned* cnt = sync;
    unsigned* gen = sync + 1;

    f16* h0b[2] = { h16, h16 + 2 * NH };
    f16* h1b[2] = { h16 + NH, h16 + 3 * NH };
    float* h0f[2] = { hf, hf + 2 * NH };
    float* h1f[2] = { hf + NH, hf + 3 * NH };

    // ---- encoder ----
    for (int t = 0; t < S_LEN; t++) {
        int p = t & 1;
        gru_phase(lds, bid, tid, mr, nc,
                  xe + (size_t)t * NB * EDIM, false,
                  h0b[p], h0f[p],
                  w_eih, w_ehh, enc_bih, enc_bhh,
                  h0b[p ^ 1], h0f[p ^ 1], (f16*)nullptr, (float*)nullptr);
        gbar(cnt, gen);
        gru_phase(lds, bid, tid, mr, nc,
                  h0b[p ^ 1], true,
                  h1b[p], h1f[p],
                  w_eih + (size_t)3 * HDIM * EDIM, w_ehh + (size_t)3 * HDIM * HDIM,
                  enc_bih + 3 * HDIM, enc_bhh + 3 * HDIM,
                  h1b[p ^ 1], h1f[p ^ 1], enc16 + (size_t)t * NH, (float*)nullptr);
        gbar(cnt, gen);
    }

    // ---- decoder ----
    for (int t = 0; t < S_LEN; t++) {
        int p = t & 1;
        attn_phase(lds, bid, tid,
                   xe + (size_t)t * NB * EDIM, h0b[p], h1b[p],
                   w_attn, attn_b, enc16, appl);
        gbar(cnt, gen);
        comb_phase(lds, bid, tid, mr, nc,
                   xe + (size_t)t * NB * EDIM, appl, w_comb, comb_b, xcur);
        gbar(cnt, gen);
        gru_phase(lds, bid, tid, mr, nc,
                  xcur, true,
                  h0b[p], h0f[p],
                  w_dih, w_dhh, dec_bih, dec_bhh,
                  h0b[p ^ 1], h0f[p ^ 1], (f16*)nullptr, (float*)nullptr);
        gbar(cnt, gen);
        gru_phase(lds, bid, tid, mr, nc,
                  h0b[p ^ 1], true,
                  h1b[p], h1f[p],
                  w_dih + (size_t)3 * HDIM * HDIM, w_dhh + (size_t)3 * HDIM * HDIM,
                  dec_bih + 3 * HDIM, dec_bhh + 3 * HDIM,
                  h1b[p ^ 1], h1f[p ^ 1], (f16*)nullptr, out + (size_t)t * NH);
        gbar(cnt, gen);
    }

    // ---- hT tail: out[S*NH .. S*NH+2NH) = hf[0 .. 2NH) ----
    if (tid < 512) {
        size_t idx = (size_t)bid * 512 + tid;
        f32x4 v;
        sysld_issue_f32x4(v, hf + idx * 4);
        sys_wait();
        sysst_f32x4(out + (size_t)S_LEN * NH + idx * 4, v);
    }
}

extern "C" void kernel_launch(void* const* d_in, const int* in_sizes, int n_in,
                              void* d_out, int out_size, void* d_ws, size_t ws_size,
                              hipStream_t stream) {
    const int*   tokens   = (const int*)d_in[0];
    const float* hidden   = (const float*)d_in[1];
    const float* emb      = (const float*)d_in[2];
    const float* enc_wih  = (const float*)d_in[3];
    const float* enc_whh  = (const float*)d_in[4];
    const float* enc_bih  = (const float*)d_in[5];
    const float* enc_bhh  = (const float*)d_in[6];
    const float* dec_wih  = (const float*)d_in[7];
    const float* dec_whh  = (const float*)d_in[8];
    const float* dec_bih  = (const float*)d_in[9];
    const float* dec_bhh  = (const float*)d_in[10];
    const float* attn_w   = (const float*)d_in[11];
    const float* attn_b   = (const float*)d_in[12];
    const float* comb_w   = (const float*)d_in[13];
    const float* comb_b   = (const float*)d_in[14];
    float* out = (float*)d_out;

    const size_t NH = (size_t)NB * HDIM;             // 262144
    const size_t WSZ = (size_t)2 * 3 * HDIM * EDIM;  // 6291456

    float* hf = (float*)d_ws;                        // 4*NH f32
    f16* wp = (f16*)(hf + 4 * NH);
    f16 *w_eih = wp;  wp += WSZ;
    f16 *w_ehh = wp;  wp += WSZ;
    f16 *w_dih = wp;  wp += WSZ;
    f16 *w_dhh = wp;  wp += WSZ;
    f16 *w_comb = wp; wp += (size_t)HDIM * 2048;
    f16 *w_attn = wp; wp += (size_t)S_LEN * 3072;
    f16 *xe = wp;     wp += (size_t)S_LEN * NB * EDIM;
    f16 *enc16 = wp;  wp += (size_t)S_LEN * NH;
    f16 *h16 = wp;    wp += 4 * NH;
    f16 *appl = wp;   wp += NH;
    f16 *xcur = wp;   wp += NH;
    unsigned* syncp = (unsigned*)((((uintptr_t)wp) + 255) & ~(uintptr_t)255);

    k_init_sync<<<1, 1, 0, stream>>>(syncp);

    k_cvt4<<<(int)(WSZ / 4 / 256), 256, 0, stream>>>(enc_wih, w_eih, (int)(WSZ / 4));
    k_cvt4<<<(int)(WSZ / 4 / 256), 256, 0, stream>>>(enc_whh, w_ehh, (int)(WSZ / 4));
    k_cvt4<<<(int)(WSZ / 4 / 256), 256, 0, stream>>>(dec_wih, w_dih, (int)(WSZ / 4));
    k_cvt4<<<(int)(WSZ / 4 / 256), 256, 0, stream>>>(dec_whh, w_dhh, (int)(WSZ / 4));
    k_cvt4<<<(int)(HDIM * 2048 / 4 / 256), 256, 0, stream>>>(comb_w, w_comb,
                                                             HDIM * 2048 / 4);
    k_cvt4<<<(S_LEN * 3072 / 4 + 255) / 256, 256, 0, stream>>>(attn_w, w_attn,
                                                               S_LEN * 3072 / 4);
    k_embed_cvt<<<S_LEN * NB, 256, 0, stream>>>(tokens, emb, xe);
    k_cvt4<<<(int)(2 * NH / 4 / 256), 256, 0, stream>>>(hidden, h16, (int)(2 * NH / 4));
    k_copyf4<<<(int)(2 * NH / 4 / 256), 256, 0, stream>>>(hidden, hf, (int)(2 * NH / 4));

    k_mega<<<NBLK, NTHR, 0, stream>>>(
        xe, h16, hf,
        w_eih, w_ehh, enc_bih, enc_bhh,
        w_dih, w_dhh, dec_bih, dec_bhh,
        w_attn, attn_b, w_comb, comb_b,
        enc16, appl, xcur, out, syncp);
}